// Round 8
// baseline (568.362 us; speedup 1.0000x reference)
//
#include <hip/hip_runtime.h>

// PCEN: out = (x/(FLOOR+m)^alpha + delta)^(1/root) - delta^(1/root)
// m = EMA over T with s=0.025, m_0 = x_0.
// Shapes: x [B=64, T=4096, C=128] f32, alpha/delta/root [C] f32.
//
// R7->R8: single-kernel fusion via depth-1 producer/consumer handshake.
// Key fact: super-chunk (128-step) end values E have NO serial dependency --
// each block computes E locally from its own x slice. A block only needs the
// E of its <=SWIN=4 predecessor supers (0.975^512 ~ 2.4e-6 truncation).
//  - block (b,sc): 256 thr = 8 chunks x 32 cg; x slice held in registers
//    (16 float4/thread), chunk ends -> LDS, E -> supv + RELEASE flag.
//  - consumers ACQUIRE-spin predecessor flags (agent scope, Guideline 16),
//    fold E's, add LDS sub-chunk prefix, then fused EMA+PCEN from registers.
//  - bounded spin + deterministic fallback (recompute E from x, identical op
//    order) => no dispatch-order assumption, no hang possible.
// Removes: k_final's L3 x re-read, endv traffic, one dispatch + gap.

constexpr int Bn = 64, Tn = 4096, Cn = 128;
constexpr int Lc = 16;            // timesteps per chunk
constexpr int SUPER = 8;          // chunks per super-chunk (= per block)
constexpr int NSUP = 32;          // supers per batch (32*8*16 = 4096)
constexpr int SWIN = 4;           // super window: 4*128 = 512 steps history
constexpr float SC  = 0.025f;
constexpr float OMS = 1.0f - SC;  // 0.975
constexpr float FLOORV = 1e-6f;
constexpr int SPIN_LIMIT = 20000; // ~10ms worst case, then fallback

typedef float v4f __attribute__((ext_vector_type(4)));

__host__ __device__ constexpr float powN(float a, int n) {
    float r = 1.0f;
    for (int i = 0; i < n; ++i) r *= a;
    return r;
}
constexpr float ACH  = powN(OMS, Lc);          // 0.975^16  ~ 0.6672
constexpr float ACHS = powN(OMS, Lc * SUPER);  // 0.975^128 ~ 0.03919

__device__ __forceinline__ float pcen_elem(float x, float m, float al, float dl,
                                           float oor, float t3) {
    float lg   = __builtin_amdgcn_logf(FLOORV + m);   // v_log_f32: log2
    float inv1 = __builtin_amdgcn_exp2f(-al * lg);    // 1 / (FLOOR+m)^alpha
    float base = fmaf(x, inv1, dl);                   // x/term1 + delta  (>0)
    return __builtin_amdgcn_exp2f(oor * __builtin_amdgcn_logf(base)) - t3;
}

__global__ __launch_bounds__(256) void k_pcen(const float* __restrict__ x,
                                              const float* __restrict__ alpha,
                                              const float* __restrict__ delta,
                                              const float* __restrict__ root,
                                              unsigned int* __restrict__ supv,
                                              int* __restrict__ flags,
                                              float* __restrict__ out) {
    const int sc  = blockIdx.x & (NSUP - 1);
    const int b   = blockIdx.x >> 5;
    const int cg  = threadIdx.x & 31;
    const int sub = threadIdx.x >> 5;
    const int chunk = sc * SUPER + sub;

    const size_t xoff = (size_t)(b * Tn + chunk * Lc) * (Cn / 4) + cg;
    const float4* xp = (const float4*)x + xoff;

    // ---- load the chunk's x into registers (held through the whole kernel)
    float4 xr[Lc];
#pragma unroll
    for (int t = 0; t < Lc; ++t) xr[t] = xp[(size_t)t * (Cn / 4)];

    // ---- chunk-local EMA fold (chunk 0: m starts at x_0)
    float4 m;
    if (chunk == 0) {
        m = xr[0];
    } else {
        m.x = SC * xr[0].x; m.y = SC * xr[0].y; m.z = SC * xr[0].z; m.w = SC * xr[0].w;
    }
#pragma unroll
    for (int t = 1; t < Lc; ++t) {
        m.x = fmaf(OMS, m.x, SC * xr[t].x);
        m.y = fmaf(OMS, m.y, SC * xr[t].y);
        m.z = fmaf(OMS, m.z, SC * xr[t].z);
        m.w = fmaf(OMS, m.w, SC * xr[t].w);
    }

    __shared__ float4 lds[SUPER][32];
    lds[sub][cg] = m;
    __syncthreads();

    // ---- publish super-end E (threads of the last chunk; 32 cg lanes)
    if (sub == SUPER - 1) {
        float4 E = lds[0][cg];
#pragma unroll
        for (int i = 1; i < SUPER; ++i) {
            float4 e = lds[i][cg];
            E.x = fmaf(ACH, E.x, e.x);
            E.y = fmaf(ACH, E.y, e.y);
            E.z = fmaf(ACH, E.z, e.z);
            E.w = fmaf(ACH, E.w, e.w);
        }
        unsigned int* dst = supv + ((size_t)blockIdx.x * 32 + cg) * 4;
        __hip_atomic_store(dst + 0, __float_as_uint(E.x), __ATOMIC_RELAXED, __HIP_MEMORY_SCOPE_AGENT);
        __hip_atomic_store(dst + 1, __float_as_uint(E.y), __ATOMIC_RELAXED, __HIP_MEMORY_SCOPE_AGENT);
        __hip_atomic_store(dst + 2, __float_as_uint(E.z), __ATOMIC_RELAXED, __HIP_MEMORY_SCOPE_AGENT);
        __hip_atomic_store(dst + 3, __float_as_uint(E.w), __ATOMIC_RELAXED, __HIP_MEMORY_SCOPE_AGENT);
        __hip_atomic_fetch_add(&flags[blockIdx.x], 1, __ATOMIC_RELEASE, __HIP_MEMORY_SCOPE_AGENT);
    }

    // ---- super prefix: fold E_{s0..sc-1} with ACHS weights
    float4 acc = {0.f, 0.f, 0.f, 0.f};
    int s0 = sc - SWIN; if (s0 < 0) s0 = 0;
    for (int s = s0; s < sc; ++s) {
        const int fbid = (b << 5) + s;        // predecessor block id (smaller)
        int f = 0, spins = 0;
        for (;;) {
            f = __hip_atomic_load(&flags[fbid], __ATOMIC_ACQUIRE, __HIP_MEMORY_SCOPE_AGENT);
            if (f >= 32) break;
            if (++spins > SPIN_LIMIT) break;
            __builtin_amdgcn_s_sleep(8);
        }
        float4 E;
        if (f >= 32) {
            const unsigned int* sp = supv + ((size_t)fbid * 32 + cg) * 4;
            E.x = __uint_as_float(__hip_atomic_load(sp + 0, __ATOMIC_RELAXED, __HIP_MEMORY_SCOPE_AGENT));
            E.y = __uint_as_float(__hip_atomic_load(sp + 1, __ATOMIC_RELAXED, __HIP_MEMORY_SCOPE_AGENT));
            E.z = __uint_as_float(__hip_atomic_load(sp + 2, __ATOMIC_RELAXED, __HIP_MEMORY_SCOPE_AGENT));
            E.w = __uint_as_float(__hip_atomic_load(sp + 3, __ATOMIC_RELAXED, __HIP_MEMORY_SCOPE_AGENT));
        } else {
            // deterministic fallback: recompute E_s from x (bit-identical
            // op order to the producer path) -- no dispatch-order assumption.
            E = {0.f, 0.f, 0.f, 0.f};
            for (int j = 0; j < SUPER; ++j) {
                int cj = s * SUPER + j;
                const float4* q = (const float4*)x + (size_t)(b * Tn + cj * Lc) * (Cn / 4) + cg;
                float4 v0 = q[0];
                float4 e;
                if (cj == 0) {
                    e = v0;
                } else {
                    e.x = SC * v0.x; e.y = SC * v0.y; e.z = SC * v0.z; e.w = SC * v0.w;
                }
                for (int t = 1; t < Lc; ++t) {
                    float4 v = q[(size_t)t * (Cn / 4)];
                    e.x = fmaf(OMS, e.x, SC * v.x);
                    e.y = fmaf(OMS, e.y, SC * v.y);
                    e.z = fmaf(OMS, e.z, SC * v.z);
                    e.w = fmaf(OMS, e.w, SC * v.w);
                }
                if (j == 0) {
                    E = e;
                } else {
                    E.x = fmaf(ACH, E.x, e.x);
                    E.y = fmaf(ACH, E.y, e.y);
                    E.z = fmaf(ACH, E.z, e.z);
                    E.w = fmaf(ACH, E.w, e.w);
                }
            }
        }
        acc.x = fmaf(ACHS, acc.x, E.x);
        acc.y = fmaf(ACHS, acc.y, E.y);
        acc.z = fmaf(ACHS, acc.z, E.z);
        acc.w = fmaf(ACHS, acc.w, E.w);
    }

    // ---- sub-chunk prefix within the super (LDS, same fold order as R7)
#pragma unroll 7
    for (int j = 0; j < sub; ++j) {
        float4 e = lds[j][cg];
        acc.x = fmaf(ACH, acc.x, e.x);
        acc.y = fmaf(ACH, acc.y, e.y);
        acc.z = fmaf(ACH, acc.z, e.z);
        acc.w = fmaf(ACH, acc.w, e.w);
    }

    // ---- per-channel params (precise one-time transcendentals)
    int c0 = cg * 4;
    float4 al = *(const float4*)(alpha + c0);
    float4 dl = *(const float4*)(delta + c0);
    float4 rt = *(const float4*)(root + c0);
    al.x = fminf(al.x, 1.f); al.y = fminf(al.y, 1.f); al.z = fminf(al.z, 1.f); al.w = fminf(al.w, 1.f);
    rt.x = fmaxf(rt.x, 1.f); rt.y = fmaxf(rt.y, 1.f); rt.z = fmaxf(rt.z, 1.f); rt.w = fmaxf(rt.w, 1.f);
    float4 oor = {1.f / rt.x, 1.f / rt.y, 1.f / rt.z, 1.f / rt.w};
    float4 t3  = {exp2f(oor.x * log2f(dl.x)), exp2f(oor.y * log2f(dl.y)),
                  exp2f(oor.z * log2f(dl.z)), exp2f(oor.w * log2f(dl.w))};

    // ---- fused EMA + PCEN from registers (no x re-read)
    v4f* op = (v4f*)out + xoff;
    if (chunk == 0) {
        m = xr[0];
    } else {
        m.x = fmaf(OMS, acc.x, SC * xr[0].x);
        m.y = fmaf(OMS, acc.y, SC * xr[0].y);
        m.z = fmaf(OMS, acc.z, SC * xr[0].z);
        m.w = fmaf(OMS, acc.w, SC * xr[0].w);
    }
    v4f o;
    o.x = pcen_elem(xr[0].x, m.x, al.x, dl.x, oor.x, t3.x);
    o.y = pcen_elem(xr[0].y, m.y, al.y, dl.y, oor.y, t3.y);
    o.z = pcen_elem(xr[0].z, m.z, al.z, dl.z, oor.z, t3.z);
    o.w = pcen_elem(xr[0].w, m.w, al.w, dl.w, oor.w, t3.w);
    __builtin_nontemporal_store(o, op);
#pragma unroll
    for (int t = 1; t < Lc; ++t) {
        m.x = fmaf(OMS, m.x, SC * xr[t].x);
        m.y = fmaf(OMS, m.y, SC * xr[t].y);
        m.z = fmaf(OMS, m.z, SC * xr[t].z);
        m.w = fmaf(OMS, m.w, SC * xr[t].w);
        o.x = pcen_elem(xr[t].x, m.x, al.x, dl.x, oor.x, t3.x);
        o.y = pcen_elem(xr[t].y, m.y, al.y, dl.y, oor.y, t3.y);
        o.z = pcen_elem(xr[t].z, m.z, al.z, dl.z, oor.z, t3.z);
        o.w = pcen_elem(xr[t].w, m.w, al.w, dl.w, oor.w, t3.w);
        __builtin_nontemporal_store(o, op + (size_t)t * (Cn / 4));
    }
}

extern "C" void kernel_launch(void* const* d_in, const int* in_sizes, int n_in,
                              void* d_out, int out_size, void* d_ws, size_t ws_size,
                              hipStream_t stream) {
    const float* x     = (const float*)d_in[0];
    const float* alpha = (const float*)d_in[1];
    const float* delta = (const float*)d_in[2];
    const float* root  = (const float*)d_in[3];
    float* out = (float*)d_out;

    // ws layout: supv (Bn*NSUP*Cn uints = 1 MiB) | flags (Bn*NSUP ints = 8 KiB)
    unsigned int* supv = (unsigned int*)d_ws;
    int* flags = (int*)((char*)d_ws + (size_t)Bn * NSUP * Cn * 4);

    hipMemsetAsync(flags, 0, Bn * NSUP * sizeof(int), stream);
    const int nblocks = Bn * NSUP;               // 2048 blocks, 256 threads
    k_pcen<<<nblocks, 256, 0, stream>>>(x, alpha, delta, root, supv, flags, out);
}

// Round 9
// 254.334 us; speedup vs baseline: 2.2347x; 2.2347x over previous
//
#include <hip/hip_runtime.h>

// PCEN: out = (x/(FLOOR+m)^alpha + delta)^(1/root) - delta^(1/root)
// m = EMA over T with s=0.025, m_0 = x_0.
// Shapes: x [B=64, T=4096, C=128] f32, alpha/delta/root [C] f32.
//
// R8 lesson (2nd failed fusion): cross-workgroup sync (grid.sync OR
// flag-handshake) costs >150us on this chip; a dispatch boundary costs ~10us.
// Keep two kernels; shrink the cross-kernel state to supv (1 MiB) only.
//
//  k_super: block = (b, sc) = 8 chunks x 32 cg. Per-thread chunk-local EMA
//           end -> LDS -> fold 8 -> super-chunk (128-step) end E -> supv.
//  k_pcen2: same block mapping. x slice in REGISTERS (16 float4/thread),
//           chunk ends -> LDS (free sub-prefix within the super; replaces
//           R7's 8 MiB endv + ~60 MiB L2 prefix traffic), super prefix =
//           <=SWIN=4 coalesced loads from L2-hot supv (0.975^512 ~ 2.4e-6
//           truncation), then fused EMA+PCEN from registers, NT stores.

constexpr int Bn = 64, Tn = 4096, Cn = 128;
constexpr int Lc = 16;            // timesteps per chunk
constexpr int SUPER = 8;          // chunks per super-chunk (= per block)
constexpr int NSUP = 32;          // supers per batch (32*8*16 = 4096)
constexpr int SWIN = 4;           // super window: 4*128 = 512 steps history
constexpr float SC  = 0.025f;
constexpr float OMS = 1.0f - SC;  // 0.975
constexpr float FLOORV = 1e-6f;

typedef float v4f __attribute__((ext_vector_type(4)));

__host__ __device__ constexpr float powN(float a, int n) {
    float r = 1.0f;
    for (int i = 0; i < n; ++i) r *= a;
    return r;
}
constexpr float ACH  = powN(OMS, Lc);          // 0.975^16  ~ 0.6672
constexpr float ACHS = powN(OMS, Lc * SUPER);  // 0.975^128 ~ 0.03919

__device__ __forceinline__ float pcen_elem(float x, float m, float al, float dl,
                                           float oor, float t3) {
    float lg   = __builtin_amdgcn_logf(FLOORV + m);   // v_log_f32: log2
    float inv1 = __builtin_amdgcn_exp2f(-al * lg);    // 1 / (FLOOR+m)^alpha
    float base = fmaf(x, inv1, dl);                   // x/term1 + delta  (>0)
    return __builtin_amdgcn_exp2f(oor * __builtin_amdgcn_logf(base)) - t3;
}

// ---------------- kernel 1: super-chunk end values ----------------
__global__ __launch_bounds__(256) void k_super(const float* __restrict__ x,
                                               float* __restrict__ supv) {
    const int sc  = blockIdx.x & (NSUP - 1);
    const int b   = blockIdx.x >> 5;
    const int cg  = threadIdx.x & 31;
    const int sub = threadIdx.x >> 5;
    const int chunk = sc * SUPER + sub;

    const float4* xp = (const float4*)x + (size_t)(b * Tn + chunk * Lc) * (Cn / 4) + cg;

    // chunk-local EMA fold (chunk 0 of the sequence: m starts at x_0)
    float4 v = xp[0];
    float4 m;
    if (chunk == 0) {
        m = v;
    } else {
        m.x = SC * v.x; m.y = SC * v.y; m.z = SC * v.z; m.w = SC * v.w;
    }
#pragma unroll
    for (int t = 1; t < Lc; ++t) {
        v = xp[(size_t)t * (Cn / 4)];
        m.x = fmaf(OMS, m.x, SC * v.x);
        m.y = fmaf(OMS, m.y, SC * v.y);
        m.z = fmaf(OMS, m.z, SC * v.z);
        m.w = fmaf(OMS, m.w, SC * v.w);
    }

    __shared__ float4 lds[SUPER][32];
    lds[sub][cg] = m;
    __syncthreads();

    if (threadIdx.x < 32) {                 // one thread per cg
        float4 E = lds[0][threadIdx.x];
#pragma unroll
        for (int i = 1; i < SUPER; ++i) {
            float4 e = lds[i][threadIdx.x];
            E.x = fmaf(ACH, E.x, e.x);
            E.y = fmaf(ACH, E.y, e.y);
            E.z = fmaf(ACH, E.z, e.z);
            E.w = fmaf(ACH, E.w, e.w);
        }
        ((float4*)supv)[(size_t)blockIdx.x * 32 + threadIdx.x] = E;
    }
}

// ---------------- kernel 2: fused prefix + EMA + PCEN ----------------
__global__ __launch_bounds__(256) void k_pcen2(const float* __restrict__ x,
                                               const float* __restrict__ alpha,
                                               const float* __restrict__ delta,
                                               const float* __restrict__ root,
                                               const float* __restrict__ supv,
                                               float* __restrict__ out) {
    const int sc  = blockIdx.x & (NSUP - 1);
    const int b   = blockIdx.x >> 5;
    const int cg  = threadIdx.x & 31;
    const int sub = threadIdx.x >> 5;
    const int chunk = sc * SUPER + sub;

    const size_t xoff = (size_t)(b * Tn + chunk * Lc) * (Cn / 4) + cg;
    const float4* xp = (const float4*)x + xoff;

    // x slice in registers (16 float4 = 64 VGPR), mostly L3-hit reads
    float4 xr[Lc];
#pragma unroll
    for (int t = 0; t < Lc; ++t) xr[t] = xp[(size_t)t * (Cn / 4)];

    // chunk-local EMA end -> LDS
    float4 m;
    if (chunk == 0) {
        m = xr[0];
    } else {
        m.x = SC * xr[0].x; m.y = SC * xr[0].y; m.z = SC * xr[0].z; m.w = SC * xr[0].w;
    }
#pragma unroll
    for (int t = 1; t < Lc; ++t) {
        m.x = fmaf(OMS, m.x, SC * xr[t].x);
        m.y = fmaf(OMS, m.y, SC * xr[t].y);
        m.z = fmaf(OMS, m.z, SC * xr[t].z);
        m.w = fmaf(OMS, m.w, SC * xr[t].w);
    }
    __shared__ float4 lds[SUPER][32];
    lds[sub][cg] = m;
    __syncthreads();

    // super prefix from supv (L2-hot, <=4 coalesced loads)
    float4 acc = {0.f, 0.f, 0.f, 0.f};
    {
        const float4* Ep = (const float4*)supv + (size_t)b * NSUP * 32 + cg;
        int s0 = sc - SWIN; if (s0 < 0) s0 = 0;
#pragma unroll 4
        for (int s = s0; s < sc; ++s) {
            float4 E = Ep[(size_t)s * 32];
            acc.x = fmaf(ACHS, acc.x, E.x);
            acc.y = fmaf(ACHS, acc.y, E.y);
            acc.z = fmaf(ACHS, acc.z, E.z);
            acc.w = fmaf(ACHS, acc.w, E.w);
        }
    }
    // sub-chunk prefix within the super (LDS, same fold order as R7/R8)
#pragma unroll 7
    for (int j = 0; j < sub; ++j) {
        float4 e = lds[j][cg];
        acc.x = fmaf(ACH, acc.x, e.x);
        acc.y = fmaf(ACH, acc.y, e.y);
        acc.z = fmaf(ACH, acc.z, e.z);
        acc.w = fmaf(ACH, acc.w, e.w);
    }

    // per-channel params (precise one-time transcendentals)
    int c0 = cg * 4;
    float4 al = *(const float4*)(alpha + c0);
    float4 dl = *(const float4*)(delta + c0);
    float4 rt = *(const float4*)(root + c0);
    al.x = fminf(al.x, 1.f); al.y = fminf(al.y, 1.f); al.z = fminf(al.z, 1.f); al.w = fminf(al.w, 1.f);
    rt.x = fmaxf(rt.x, 1.f); rt.y = fmaxf(rt.y, 1.f); rt.z = fmaxf(rt.z, 1.f); rt.w = fmaxf(rt.w, 1.f);
    float4 oor = {1.f / rt.x, 1.f / rt.y, 1.f / rt.z, 1.f / rt.w};
    float4 t3  = {exp2f(oor.x * log2f(dl.x)), exp2f(oor.y * log2f(dl.y)),
                  exp2f(oor.z * log2f(dl.z)), exp2f(oor.w * log2f(dl.w))};

    // fused EMA + PCEN from registers (no second x pass)
    v4f* op = (v4f*)out + xoff;
    if (chunk == 0) {
        m = xr[0];
    } else {
        m.x = fmaf(OMS, acc.x, SC * xr[0].x);
        m.y = fmaf(OMS, acc.y, SC * xr[0].y);
        m.z = fmaf(OMS, acc.z, SC * xr[0].z);
        m.w = fmaf(OMS, acc.w, SC * xr[0].w);
    }
    v4f o;
    o.x = pcen_elem(xr[0].x, m.x, al.x, dl.x, oor.x, t3.x);
    o.y = pcen_elem(xr[0].y, m.y, al.y, dl.y, oor.y, t3.y);
    o.z = pcen_elem(xr[0].z, m.z, al.z, dl.z, oor.z, t3.z);
    o.w = pcen_elem(xr[0].w, m.w, al.w, dl.w, oor.w, t3.w);
    __builtin_nontemporal_store(o, op);
#pragma unroll
    for (int t = 1; t < Lc; ++t) {
        m.x = fmaf(OMS, m.x, SC * xr[t].x);
        m.y = fmaf(OMS, m.y, SC * xr[t].y);
        m.z = fmaf(OMS, m.z, SC * xr[t].z);
        m.w = fmaf(OMS, m.w, SC * xr[t].w);
        o.x = pcen_elem(xr[t].x, m.x, al.x, dl.x, oor.x, t3.x);
        o.y = pcen_elem(xr[t].y, m.y, al.y, dl.y, oor.y, t3.y);
        o.z = pcen_elem(xr[t].z, m.z, al.z, dl.z, oor.z, t3.z);
        o.w = pcen_elem(xr[t].w, m.w, al.w, dl.w, oor.w, t3.w);
        __builtin_nontemporal_store(o, op + (size_t)t * (Cn / 4));
    }
}

extern "C" void kernel_launch(void* const* d_in, const int* in_sizes, int n_in,
                              void* d_out, int out_size, void* d_ws, size_t ws_size,
                              hipStream_t stream) {
    const float* x     = (const float*)d_in[0];
    const float* alpha = (const float*)d_in[1];
    const float* delta = (const float*)d_in[2];
    const float* root  = (const float*)d_in[3];
    float* out  = (float*)d_out;
    float* supv = (float*)d_ws;                  // 1 MiB

    const int nblocks = Bn * NSUP;               // 2048 blocks, 256 threads
    k_super<<<nblocks, 256, 0, stream>>>(x, supv);
    k_pcen2<<<nblocks, 256, 0, stream>>>(x, alpha, delta, root, supv, out);
}